// Round 1
// baseline (155.583 us; speedup 1.0000x reference)
//
#include <hip/hip_runtime.h>
#include <math.h>

// ---- constants (double-precision folds to float at compile time) ----
static constexpr double D_CUTOFF   = 7.0;
static constexpr double D_SIGMA    = 3.1589;
static constexpr double D_EPS      = 0.1852;
static constexpr double D_GAMMA    = 0.73612;
static constexpr double D_Q        = 1.1128;
static constexpr double D_OH_EQ    = 0.9419;
static constexpr double D_OH_K     = 1059.162;
static constexpr double D_OH_ALPHA = 2.287;
static constexpr double D_ANG_EQ   = 1.87448;
static constexpr double D_ANG_K    = 87.85;
static constexpr double D_SMEAR    = 1.4;
static constexpr double D_PREF     = 332.0637133;

static constexpr double D_SC6   = (D_SIGMA/D_CUTOFF)*(D_SIGMA/D_CUTOFF)*(D_SIGMA/D_CUTOFF)
                                * (D_SIGMA/D_CUTOFF)*(D_SIGMA/D_CUTOFF)*(D_SIGMA/D_CUTOFF);
static constexpr float F_SIG2      = (float)(D_SIGMA*D_SIGMA);
static constexpr float F_4EPS      = (float)(4.0*D_EPS);
static constexpr float F_LJ_SHIFT  = (float)(-4.0*D_EPS*D_SC6*(D_SC6-1.0));
static constexpr float F_Q         = (float)D_Q;
static constexpr float F_QO        = (float)(-D_Q);
static constexpr float F_QH        = (float)(0.5*D_Q);
static constexpr float F_PREF      = (float)D_PREF;
static constexpr float F_INV_S2S   = (float)(1.0/(1.4142135623730951*D_SMEAR));
static constexpr float F_OMG       = (float)((1.0-D_GAMMA)*0.5);
static constexpr float F_OH_EQ     = (float)D_OH_EQ;
static constexpr float F_OH_K      = (float)D_OH_K;
static constexpr float F_OH_ALPHA  = (float)D_OH_ALPHA;
static constexpr float F_ANG_EQ    = (float)D_ANG_EQ;
static constexpr float F_ANG_K     = (float)D_ANG_K;

// ---- fast erfc (A&S 7.1.26, |abs err| <= 1.5e-7) ----
__device__ __forceinline__ float fast_erfc(float x) {
    const float t = __builtin_amdgcn_rcpf(fmaf(0.3275911f, x, 1.0f));
    float p = fmaf(1.061405429f, t, -1.453152027f);
    p = fmaf(p, t, 1.421413741f);
    p = fmaf(p, t, -0.284496736f);
    p = fmaf(p, t, 0.254829592f);
    p *= t;
    return p * __expf(-x * x);
}

// ---- block-wide sum; returns total at thread 0 (undefined elsewhere) ----
__device__ __forceinline__ float block_reduce(float v) {
#pragma unroll
    for (int o = 32; o > 0; o >>= 1) v += __shfl_down(v, o, 64);
    __shared__ float smem[8];
    const int lane = threadIdx.x & 63;
    const int w    = threadIdx.x >> 6;
    if (lane == 0) smem[w] = v;
    __syncthreads();
    float t = 0.f;
    if (threadIdx.x == 0) {
        const int nw = (blockDim.x + 63) >> 6;
        for (int k = 0; k < nw; ++k) t += smem[k];
    }
    return t;
}

__device__ __forceinline__ float bond_e(float r) {
    const float dr  = r - F_OH_EQ;
    const float adr = dr * F_OH_ALPHA;
    return 0.5f * F_OH_K * dr * dr * (1.f - adr + adr * adr * (7.f / 12.f));
}

// ---- kernel 1: per-molecule bond/bend/self energies + om vector ----
// Pair m (m<n_mol) is the O->H1 bond of molecule m; pair n_mol+m is O->H2.
// Bonds (r~0.96A << 7A) survive the cutoff filter with order preserved.
// Also zeroes the accumulator + ticket used by kernel 2's finalize.
__global__ void k_bond(const float* __restrict__ dij, float4* __restrict__ om,
                       float* __restrict__ partial, float* __restrict__ acc,
                       unsigned* __restrict__ ticket, int n_mol) {
    const int m = blockIdx.x * blockDim.x + threadIdx.x;
    if (m == 0) { *acc = 0.f; *ticket = 0u; }
    float e = 0.f;
    if (m < n_mol) {
        const float* d1 = dij + 3 * (size_t)m;
        const float* d2 = dij + 3 * (size_t)(n_mol + m);
        const float x1 = d1[0], y1 = d1[1], z1 = d1[2];
        const float x2 = d2[0], y2 = d2[1], z2 = d2[2];
        const float r1 = sqrtf(x1*x1 + y1*y1 + z1*z1);
        const float r2 = sqrtf(x2*x2 + y2*y2 + z2*z2);
        e += bond_e(r1) + bond_e(r2);
        const float ca  = (x1*x2 + y1*y2 + z1*z2) * __builtin_amdgcn_rcpf(r1 * r2);
        const float da  = acosf(ca) - F_ANG_EQ;
        e += 0.5f * F_ANG_K * da * da;
        const float ox = F_OMG * (x1 + x2), oy = F_OMG * (y1 + y2), oz = F_OMG * (z1 + z2);
        om[m] = make_float4(ox, oy, oz, 0.f);
        // minus e_self = (inv_mh*Q - inv_hh*0.5Q) * 0.5Q * PREF
        const float ax = x1-ox, ay = y1-oy, az = z1-oz;
        const float bx = x2-ox, by = y2-oy, bz = z2-oz;
        const float hx = x1-x2, hy = y1-y2, hz = z1-z2;
        const float inv_mh = __builtin_amdgcn_rsqf(ax*ax+ay*ay+az*az)
                           + __builtin_amdgcn_rsqf(bx*bx+by*by+bz*bz);
        const float inv_hh = __builtin_amdgcn_rsqf(hx*hx+hy*hy+hz*hz);
        e += (inv_mh * F_Q - inv_hh * 0.5f * F_Q) * (0.5f * F_Q * F_PREF);
    }
    const float bsum = block_reduce(e);
    if (threadIdx.x == 0) partial[blockIdx.x] = bsum;
}

// ---- per-pair LJ + screened Coulomb ----
__device__ __forceinline__ float pair_e(int i, int j, float dx, float dy, float dz,
                                        const float4* __restrict__ om) {
    const unsigned mi = (unsigned)i / 3u, mj = (unsigned)j / 3u;
    const bool iO = (i == (int)(3u * mi));
    const bool jO = (j == (int)(3u * mj));
    float4 omi = make_float4(0.f, 0.f, 0.f, 0.f);
    float4 omj = make_float4(0.f, 0.f, 0.f, 0.f);
    if (iO) omi = om[mi];
    if (jO) omj = om[mj];
    const float mx = dx + omj.x - omi.x;
    const float my = dy + omj.y - omi.y;
    const float mz = dz + omj.z - omi.z;
    const float r2m   = mx*mx + my*my + mz*mz;
    const float invrm = __builtin_amdgcn_rsqf(r2m);
    const float rm    = r2m * invrm;
    const float qq = (iO ? F_QO : F_QH) * (jO ? F_QO : F_QH);
    float e = F_PREF * qq * fast_erfc(rm * F_INV_S2S) * invrm;
    if (iO && jO) {
        const float r2 = dx*dx + dy*dy + dz*dz;
        const float s2 = F_SIG2 * __builtin_amdgcn_rcpf(r2);
        const float c6 = s2 * s2 * s2;
        e += fmaf(F_4EPS, c6 * c6 - c6, F_LJ_SHIFT);
    }
    return e;
}

// ---- kernel 2: pairs 4-wide (dwordx4 streams, 4 independent gather chains)
//      + last-block finalize (replaces the former k_reduce launch) ----
__global__ __launch_bounds__(256, 4)
void k_pair(const int* __restrict__ ni, const int* __restrict__ nj,
            const float* __restrict__ dij, const float4* __restrict__ om,
            const float* __restrict__ bond_partial, int nb_bond,
            float* __restrict__ acc, unsigned* __restrict__ ticket,
            float* __restrict__ out, int n_pairs) {
    const int tid      = blockIdx.x * blockDim.x + threadIdx.x;
    const int nthreads = gridDim.x * blockDim.x;
    float e = 0.f;

    const int n4 = n_pairs >> 2;            // 4-pair chunks
    const int4*   ni4  = (const int4*)ni;
    const int4*   nj4  = (const int4*)nj;
    const float4* d4   = (const float4*)dij;
    for (int c = tid; c < n4; c += nthreads) {
        const int4   i4 = ni4[c];
        const int4   j4 = nj4[c];
        const float4 f0 = d4[3 * c + 0];
        const float4 f1 = d4[3 * c + 1];
        const float4 f2 = d4[3 * c + 2];
        e += pair_e(i4.x, j4.x, f0.x, f0.y, f0.z, om);
        e += pair_e(i4.y, j4.y, f0.w, f1.x, f1.y, om);
        e += pair_e(i4.z, j4.z, f1.z, f1.w, f2.x, om);
        e += pair_e(i4.w, j4.w, f2.y, f2.z, f2.w, om);
    }
    // tail (<4 pairs)
    for (int p = 4 * n4 + tid; p < n_pairs; p += nthreads) {
        const size_t b = 3 * (size_t)p;
        e += pair_e(ni[p], nj[p], dij[b + 0], dij[b + 1], dij[b + 2], om);
    }

    const float bsum = block_reduce(e);
    __shared__ bool is_last;
    if (threadIdx.x == 0) {
        atomicAdd(acc, bsum);
        __threadfence();
        is_last = (atomicAdd(ticket, 1u) == (unsigned)(gridDim.x - 1));
    }
    __syncthreads();
    if (is_last) {
        float v = 0.f;
        for (int k = threadIdx.x; k < nb_bond; k += blockDim.x) v += bond_partial[k];
        const float bond_sum = block_reduce(v);
        if (threadIdx.x == 0) out[0] = bond_sum + atomicAdd(acc, 0.f);
    }
}

extern "C" void kernel_launch(void* const* d_in, const int* in_sizes, int n_in,
                              void* d_out, int out_size, void* d_ws, size_t ws_size,
                              hipStream_t stream) {
    const float* dij = (const float*)d_in[0];
    const int* ni = (const int*)d_in[2];
    const int* nj = (const int*)d_in[3];
    float* out = (float*)d_out;

    const int n_atoms = in_sizes[1];
    const int n_pairs = in_sizes[2];
    const int n_mol   = n_atoms / 3;

    const int B = 256;
    const int NB_BOND = (n_mol + B - 1) / B;
    const int NB_PAIR = 2048;

    // ws layout: om [n_mol float4] | bond partials [NB_BOND] | acc [1] | ticket [1]
    float4*   om       = (float4*)d_ws;
    float*    partials = (float*)((char*)d_ws + (size_t)n_mol * sizeof(float4));
    float*    acc      = partials + NB_BOND;
    unsigned* ticket   = (unsigned*)(acc + 1);

    k_bond<<<NB_BOND, B, 0, stream>>>(dij, om, partials, acc, ticket, n_mol);
    k_pair<<<NB_PAIR, B, 0, stream>>>(ni, nj, dij, om, partials, NB_BOND,
                                      acc, ticket, out, n_pairs);
}

// Round 2
// 146.120 us; speedup vs baseline: 1.0648x; 1.0648x over previous
//
#include <hip/hip_runtime.h>
#include <math.h>

// ---- constants (double-precision folds to float at compile time) ----
static constexpr double D_CUTOFF   = 7.0;
static constexpr double D_SIGMA    = 3.1589;
static constexpr double D_EPS      = 0.1852;
static constexpr double D_GAMMA    = 0.73612;
static constexpr double D_Q        = 1.1128;
static constexpr double D_OH_EQ    = 0.9419;
static constexpr double D_OH_K     = 1059.162;
static constexpr double D_OH_ALPHA = 2.287;
static constexpr double D_ANG_EQ   = 1.87448;
static constexpr double D_ANG_K    = 87.85;
static constexpr double D_SMEAR    = 1.4;
static constexpr double D_PREF     = 332.0637133;

static constexpr double D_SC6   = (D_SIGMA/D_CUTOFF)*(D_SIGMA/D_CUTOFF)*(D_SIGMA/D_CUTOFF)
                                * (D_SIGMA/D_CUTOFF)*(D_SIGMA/D_CUTOFF)*(D_SIGMA/D_CUTOFF);
static constexpr float F_SIG2      = (float)(D_SIGMA*D_SIGMA);
static constexpr float F_4EPS      = (float)(4.0*D_EPS);
static constexpr float F_LJ_SHIFT  = (float)(-4.0*D_EPS*D_SC6*(D_SC6-1.0));
static constexpr float F_Q         = (float)D_Q;
static constexpr float F_QO        = (float)(-D_Q);
static constexpr float F_QH        = (float)(0.5*D_Q);
static constexpr float F_PREF      = (float)D_PREF;
static constexpr float F_INV_S2S   = (float)(1.0/(1.4142135623730951*D_SMEAR));
static constexpr float F_OMG       = (float)((1.0-D_GAMMA)*0.5);
static constexpr float F_OH_EQ     = (float)D_OH_EQ;
static constexpr float F_OH_K      = (float)D_OH_K;
static constexpr float F_OH_ALPHA  = (float)D_OH_ALPHA;
static constexpr float F_ANG_EQ    = (float)D_ANG_EQ;
static constexpr float F_ANG_K     = (float)D_ANG_K;

// ---- fast erfc (A&S 7.1.26, |abs err| <= 1.5e-7) ----
__device__ __forceinline__ float fast_erfc(float x) {
    const float t = __builtin_amdgcn_rcpf(fmaf(0.3275911f, x, 1.0f));
    float p = fmaf(1.061405429f, t, -1.453152027f);
    p = fmaf(p, t, 1.421413741f);
    p = fmaf(p, t, -0.284496736f);
    p = fmaf(p, t, 0.254829592f);
    p *= t;
    return p * __expf(-x * x);
}

// ---- block-wide sum; returns total at thread 0 (undefined elsewhere) ----
__device__ __forceinline__ float block_reduce(float v) {
#pragma unroll
    for (int o = 32; o > 0; o >>= 1) v += __shfl_down(v, o, 64);
    __shared__ float smem[8];
    const int lane = threadIdx.x & 63;
    const int w    = threadIdx.x >> 6;
    if (lane == 0) smem[w] = v;
    __syncthreads();
    float t = 0.f;
    if (threadIdx.x == 0) {
        const int nw = (blockDim.x + 63) >> 6;
        for (int k = 0; k < nw; ++k) t += smem[k];
    }
    return t;
}

__device__ __forceinline__ float bond_e(float r) {
    const float dr  = r - F_OH_EQ;
    const float adr = dr * F_OH_ALPHA;
    return 0.5f * F_OH_K * dr * dr * (1.f - adr + adr * adr * (7.f / 12.f));
}

// ---- kernel 1: per-molecule bond/bend/self energies + per-ATOM om3 table ----
// Pair m (m<n_mol) is the O->H1 bond of molecule m; pair n_mol+m is O->H2.
// om3[a] = (m-site offset xyz, charge w). H atoms: offset 0, charge +Q/2.
// Unconditional per-atom table lets k_pair gather without div/branch.
__global__ void k_bond(const float* __restrict__ dij, float4* __restrict__ om3,
                       float* __restrict__ partial, float* __restrict__ acc,
                       unsigned* __restrict__ ticket, int n_mol) {
    const int m = blockIdx.x * blockDim.x + threadIdx.x;
    if (m == 0) { *acc = 0.f; *ticket = 0u; }
    float e = 0.f;
    if (m < n_mol) {
        const float* d1 = dij + 3 * (size_t)m;
        const float* d2 = dij + 3 * (size_t)(n_mol + m);
        const float x1 = d1[0], y1 = d1[1], z1 = d1[2];
        const float x2 = d2[0], y2 = d2[1], z2 = d2[2];
        const float r1 = sqrtf(x1*x1 + y1*y1 + z1*z1);
        const float r2 = sqrtf(x2*x2 + y2*y2 + z2*z2);
        e += bond_e(r1) + bond_e(r2);
        const float ca  = (x1*x2 + y1*y2 + z1*z2) * __builtin_amdgcn_rcpf(r1 * r2);
        const float da  = acosf(ca) - F_ANG_EQ;
        e += 0.5f * F_ANG_K * da * da;
        const float ox = F_OMG * (x1 + x2), oy = F_OMG * (y1 + y2), oz = F_OMG * (z1 + z2);
        om3[3 * m + 0] = make_float4(ox, oy, oz, F_QO);
        om3[3 * m + 1] = make_float4(0.f, 0.f, 0.f, F_QH);
        om3[3 * m + 2] = make_float4(0.f, 0.f, 0.f, F_QH);
        // minus e_self = (inv_mh*Q - inv_hh*0.5Q) * 0.5Q * PREF
        const float ax = x1-ox, ay = y1-oy, az = z1-oz;
        const float bx = x2-ox, by = y2-oy, bz = z2-oz;
        const float hx = x1-x2, hy = y1-y2, hz = z1-z2;
        const float inv_mh = __builtin_amdgcn_rsqf(ax*ax+ay*ay+az*az)
                           + __builtin_amdgcn_rsqf(bx*bx+by*by+bz*bz);
        const float inv_hh = __builtin_amdgcn_rsqf(hx*hx+hy*hy+hz*hz);
        e += (inv_mh * F_Q - inv_hh * 0.5f * F_Q) * (0.5f * F_Q * F_PREF);
    }
    const float bsum = block_reduce(e);
    if (threadIdx.x == 0) partial[blockIdx.x] = bsum;
}

// ---- per-pair LJ + screened Coulomb (branch-free gathers) ----
__device__ __forceinline__ float pair_e(int i, int j, float dx, float dy, float dz,
                                        const float4* __restrict__ om3) {
    const float4 oi = om3[i];
    const float4 oj = om3[j];
    const float mx = dx + oj.x - oi.x;
    const float my = dy + oj.y - oi.y;
    const float mz = dz + oj.z - oi.z;
    const float r2m   = mx*mx + my*my + mz*mz;
    const float invrm = __builtin_amdgcn_rsqf(r2m);
    const float rm    = r2m * invrm;
    const float qq = oi.w * oj.w;
    float e = F_PREF * qq * fast_erfc(rm * F_INV_S2S) * invrm;
    if (oi.w < 0.f && oj.w < 0.f) {   // both oxygen -> LJ
        const float r2 = dx*dx + dy*dy + dz*dz;
        const float s2 = F_SIG2 * __builtin_amdgcn_rcpf(r2);
        const float c6 = s2 * s2 * s2;
        e += fmaf(F_4EPS, c6 * c6 - c6, F_LJ_SHIFT);
    }
    return e;
}

// ---- kernel 2: pairs 8-wide per thread (two 4-pair chunks: c and c+half)
//      10 independent dwordx4 stream loads + 16 independent gathers in flight.
//      Last-block finalize replaces a separate reduce launch. ----
__global__ void k_pair(const int* __restrict__ ni, const int* __restrict__ nj,
                       const float* __restrict__ dij, const float4* __restrict__ om3,
                       const float* __restrict__ bond_partial, int nb_bond,
                       float* __restrict__ acc, unsigned* __restrict__ ticket,
                       float* __restrict__ out, int n_pairs) {
    const int tid = blockIdx.x * blockDim.x + threadIdx.x;
    const int nth = gridDim.x * blockDim.x;
    const int n4   = n_pairs >> 2;          // 4-pair chunks
    const int half = (n4 + 1) >> 1;
    const int4*   ni4 = (const int4*)ni;
    const int4*   nj4 = (const int4*)nj;
    const float4* d4  = (const float4*)dij;
    float e = 0.f;

    for (int c = tid; c < half; c += nth) {
        const int  c1   = c + half;
        const bool has1 = (c1 < n4);
        // chunk 0 streams (coalesced per instruction)
        const int4   ia = ni4[c];
        const int4   ja = nj4[c];
        const float4 a0 = d4[3 * c + 0];
        const float4 a1 = d4[3 * c + 1];
        const float4 a2 = d4[3 * c + 2];
        // chunk 1 streams
        int4 ib, jb; float4 b0, b1, b2;
        if (has1) {
            ib = ni4[c1];
            jb = nj4[c1];
            b0 = d4[3 * c1 + 0];
            b1 = d4[3 * c1 + 1];
            b2 = d4[3 * c1 + 2];
        }
        e += pair_e(ia.x, ja.x, a0.x, a0.y, a0.z, om3);
        e += pair_e(ia.y, ja.y, a0.w, a1.x, a1.y, om3);
        e += pair_e(ia.z, ja.z, a1.z, a1.w, a2.x, om3);
        e += pair_e(ia.w, ja.w, a2.y, a2.z, a2.w, om3);
        if (has1) {
            e += pair_e(ib.x, jb.x, b0.x, b0.y, b0.z, om3);
            e += pair_e(ib.y, jb.y, b0.w, b1.x, b1.y, om3);
            e += pair_e(ib.z, jb.z, b1.z, b1.w, b2.x, om3);
            e += pair_e(ib.w, jb.w, b2.y, b2.z, b2.w, om3);
        }
    }
    // tail (<4 pairs)
    for (int p = 4 * n4 + tid; p < n_pairs; p += nth) {
        const size_t b = 3 * (size_t)p;
        e += pair_e(ni[p], nj[p], dij[b + 0], dij[b + 1], dij[b + 2], om3);
    }

    const float bsum = block_reduce(e);
    __shared__ bool is_last;
    if (threadIdx.x == 0) {
        atomicAdd(acc, bsum);
        __threadfence();
        is_last = (atomicAdd(ticket, 1u) == (unsigned)(gridDim.x - 1));
    }
    __syncthreads();
    if (is_last) {
        float v = 0.f;
        for (int k = threadIdx.x; k < nb_bond; k += blockDim.x) v += bond_partial[k];
        const float bond_sum = block_reduce(v);
        if (threadIdx.x == 0) out[0] = bond_sum + atomicAdd(acc, 0.f);
    }
}

extern "C" void kernel_launch(void* const* d_in, const int* in_sizes, int n_in,
                              void* d_out, int out_size, void* d_ws, size_t ws_size,
                              hipStream_t stream) {
    const float* dij = (const float*)d_in[0];
    const int* ni = (const int*)d_in[2];
    const int* nj = (const int*)d_in[3];
    float* out = (float*)d_out;

    const int n_atoms = in_sizes[1];
    const int n_pairs = in_sizes[2];
    const int n_mol   = n_atoms / 3;

    const int B = 256;
    const int NB_BOND = (n_mol + B - 1) / B;

    // one thread per 8 pairs (two 4-pair chunks), grid-stride covers remainder
    const int n4   = n_pairs >> 2;
    const int half = (n4 + 1) >> 1;
    int NB_PAIR = (half + B - 1) / B;
    if (NB_PAIR < 1)    NB_PAIR = 1;
    if (NB_PAIR > 8192) NB_PAIR = 8192;

    // ws layout: om3 [n_atoms float4] | bond partials [NB_BOND] | acc [1] | ticket [1]
    float4*   om3      = (float4*)d_ws;
    float*    partials = (float*)((char*)d_ws + (size_t)n_atoms * sizeof(float4));
    float*    acc      = partials + NB_BOND;
    unsigned* ticket   = (unsigned*)(acc + 1);

    k_bond<<<NB_BOND, B, 0, stream>>>(dij, om3, partials, acc, ticket, n_mol);
    k_pair<<<NB_PAIR, B, 0, stream>>>(ni, nj, dij, om3, partials, NB_BOND,
                                      acc, ticket, out, n_pairs);
}

// Round 3
// 114.182 us; speedup vs baseline: 1.3626x; 1.2797x over previous
//
#include <hip/hip_runtime.h>
#include <math.h>

// ---- constants (double-precision folds to float at compile time) ----
static constexpr double D_CUTOFF   = 7.0;
static constexpr double D_SIGMA    = 3.1589;
static constexpr double D_EPS      = 0.1852;
static constexpr double D_GAMMA    = 0.73612;
static constexpr double D_Q        = 1.1128;
static constexpr double D_OH_EQ    = 0.9419;
static constexpr double D_OH_K     = 1059.162;
static constexpr double D_OH_ALPHA = 2.287;
static constexpr double D_ANG_EQ   = 1.87448;
static constexpr double D_ANG_K    = 87.85;
static constexpr double D_SMEAR    = 1.4;
static constexpr double D_PREF     = 332.0637133;

static constexpr double D_SC6   = (D_SIGMA/D_CUTOFF)*(D_SIGMA/D_CUTOFF)*(D_SIGMA/D_CUTOFF)
                                * (D_SIGMA/D_CUTOFF)*(D_SIGMA/D_CUTOFF)*(D_SIGMA/D_CUTOFF);
static constexpr float F_SIG2      = (float)(D_SIGMA*D_SIGMA);
static constexpr float F_4EPS      = (float)(4.0*D_EPS);
static constexpr float F_LJ_SHIFT  = (float)(-4.0*D_EPS*D_SC6*(D_SC6-1.0));
static constexpr float F_Q         = (float)D_Q;
static constexpr float F_QO        = (float)(-D_Q);
static constexpr float F_QH        = (float)(0.5*D_Q);
static constexpr float F_PREF      = (float)D_PREF;
static constexpr float F_INV_S2S   = (float)(1.0/(1.4142135623730951*D_SMEAR));
static constexpr float F_OMG       = (float)((1.0-D_GAMMA)*0.5);
static constexpr float F_OH_EQ     = (float)D_OH_EQ;
static constexpr float F_OH_K      = (float)D_OH_K;
static constexpr float F_OH_ALPHA  = (float)D_OH_ALPHA;
static constexpr float F_ANG_EQ    = (float)D_ANG_EQ;
static constexpr float F_ANG_K     = (float)D_ANG_K;

// ---- fast erfc (A&S 7.1.26, |abs err| <= 1.5e-7) ----
__device__ __forceinline__ float fast_erfc(float x) {
    const float t = __builtin_amdgcn_rcpf(fmaf(0.3275911f, x, 1.0f));
    float p = fmaf(1.061405429f, t, -1.453152027f);
    p = fmaf(p, t, 1.421413741f);
    p = fmaf(p, t, -0.284496736f);
    p = fmaf(p, t, 0.254829592f);
    p *= t;
    return p * __expf(-x * x);
}

// ---- block-wide sum; thread 0 stores to *dst (no atomics, no fences) ----
__device__ __forceinline__ void block_reduce_store(float v, float* dst) {
#pragma unroll
    for (int o = 32; o > 0; o >>= 1) v += __shfl_down(v, o, 64);
    __shared__ float smem[8];
    const int lane = threadIdx.x & 63;
    const int w    = threadIdx.x >> 6;
    if (lane == 0) smem[w] = v;
    __syncthreads();
    if (threadIdx.x == 0) {
        const int nw = (blockDim.x + 63) >> 6;
        float t = 0.f;
        for (int k = 0; k < nw; ++k) t += smem[k];
        *dst = t;
    }
}

__device__ __forceinline__ float bond_e(float r) {
    const float dr  = r - F_OH_EQ;
    const float adr = dr * F_OH_ALPHA;
    return 0.5f * F_OH_K * dr * dr * (1.f - adr + adr * adr * (7.f / 12.f));
}

// ---- kernel 1: per-molecule bond/bend/self energies + per-ATOM om3 table ----
// Pair m (m<n_mol) is the O->H1 bond of molecule m; pair n_mol+m is O->H2.
// om3[a] = (m-site offset xyz, charge w). H atoms: offset 0, charge +Q/2.
// Unconditional per-atom table lets k_pair gather without div/branch.
__global__ void k_bond(const float* __restrict__ dij, float4* __restrict__ om3,
                       float* __restrict__ partial, int n_mol) {
    const int m = blockIdx.x * blockDim.x + threadIdx.x;
    float e = 0.f;
    if (m < n_mol) {
        const float* d1 = dij + 3 * (size_t)m;
        const float* d2 = dij + 3 * (size_t)(n_mol + m);
        const float x1 = d1[0], y1 = d1[1], z1 = d1[2];
        const float x2 = d2[0], y2 = d2[1], z2 = d2[2];
        const float r1 = sqrtf(x1*x1 + y1*y1 + z1*z1);
        const float r2 = sqrtf(x2*x2 + y2*y2 + z2*z2);
        e += bond_e(r1) + bond_e(r2);
        const float ca  = (x1*x2 + y1*y2 + z1*z2) * __builtin_amdgcn_rcpf(r1 * r2);
        const float da  = acosf(ca) - F_ANG_EQ;
        e += 0.5f * F_ANG_K * da * da;
        const float ox = F_OMG * (x1 + x2), oy = F_OMG * (y1 + y2), oz = F_OMG * (z1 + z2);
        om3[3 * m + 0] = make_float4(ox, oy, oz, F_QO);
        om3[3 * m + 1] = make_float4(0.f, 0.f, 0.f, F_QH);
        om3[3 * m + 2] = make_float4(0.f, 0.f, 0.f, F_QH);
        // minus e_self = (inv_mh*Q - inv_hh*0.5Q) * 0.5Q * PREF
        const float ax = x1-ox, ay = y1-oy, az = z1-oz;
        const float bx = x2-ox, by = y2-oy, bz = z2-oz;
        const float hx = x1-x2, hy = y1-y2, hz = z1-z2;
        const float inv_mh = __builtin_amdgcn_rsqf(ax*ax+ay*ay+az*az)
                           + __builtin_amdgcn_rsqf(bx*bx+by*by+bz*bz);
        const float inv_hh = __builtin_amdgcn_rsqf(hx*hx+hy*hy+hz*hz);
        e += (inv_mh * F_Q - inv_hh * 0.5f * F_Q) * (0.5f * F_Q * F_PREF);
    }
    block_reduce_store(e, partial + blockIdx.x);
}

// ---- per-pair LJ + screened Coulomb (branch-free gathers) ----
__device__ __forceinline__ float pair_e(int i, int j, float dx, float dy, float dz,
                                        const float4* __restrict__ om3) {
    const float4 oi = om3[i];
    const float4 oj = om3[j];
    const float mx = dx + oj.x - oi.x;
    const float my = dy + oj.y - oi.y;
    const float mz = dz + oj.z - oi.z;
    const float r2m   = mx*mx + my*my + mz*mz;
    const float invrm = __builtin_amdgcn_rsqf(r2m);
    const float rm    = r2m * invrm;
    const float qq = oi.w * oj.w;
    float e = F_PREF * qq * fast_erfc(rm * F_INV_S2S) * invrm;
    if (oi.w < 0.f && oj.w < 0.f) {   // both oxygen -> LJ
        const float r2 = dx*dx + dy*dy + dz*dz;
        const float s2 = F_SIG2 * __builtin_amdgcn_rcpf(r2);
        const float c6 = s2 * s2 * s2;
        e += fmaf(F_4EPS, c6 * c6 - c6, F_LJ_SHIFT);
    }
    return e;
}

// ---- kernel 2: one 4-pair chunk per thread (dwordx4 streams, 8 independent
//      gathers), concurrency from TLP (~1800 blocks). Partial store only —
//      NO atomics / fences (same-line device atomics were the r1-r2 killer). ----
__global__ void k_pair(const int* __restrict__ ni, const int* __restrict__ nj,
                       const float* __restrict__ dij, const float4* __restrict__ om3,
                       float* __restrict__ partial, int n_pairs) {
    const int tid = blockIdx.x * blockDim.x + threadIdx.x;
    const int nth = gridDim.x * blockDim.x;
    const int n4  = n_pairs >> 2;           // 4-pair chunks
    const int4*   ni4 = (const int4*)ni;
    const int4*   nj4 = (const int4*)nj;
    const float4* d4  = (const float4*)dij;
    float e = 0.f;

    for (int c = tid; c < n4; c += nth) {
        const int4   ia = ni4[c];
        const int4   ja = nj4[c];
        const float4 a0 = d4[3 * c + 0];
        const float4 a1 = d4[3 * c + 1];
        const float4 a2 = d4[3 * c + 2];
        e += pair_e(ia.x, ja.x, a0.x, a0.y, a0.z, om3);
        e += pair_e(ia.y, ja.y, a0.w, a1.x, a1.y, om3);
        e += pair_e(ia.z, ja.z, a1.z, a1.w, a2.x, om3);
        e += pair_e(ia.w, ja.w, a2.y, a2.z, a2.w, om3);
    }
    // tail (<4 pairs)
    for (int p = 4 * n4 + tid; p < n_pairs; p += nth) {
        const size_t b = 3 * (size_t)p;
        e += pair_e(ni[p], nj[p], dij[b + 0], dij[b + 1], dij[b + 2], om3);
    }

    block_reduce_store(e, partial + blockIdx.x);
}

// ---- kernel 3: final reduction of all partials -> out[0] ----
__global__ void k_reduce(const float* __restrict__ partial, int n, float* __restrict__ out) {
    float v = 0.f;
    for (int i = threadIdx.x; i < n; i += blockDim.x) v += partial[i];
#pragma unroll
    for (int o = 32; o > 0; o >>= 1) v += __shfl_down(v, o, 64);
    __shared__ float smem[8];
    const int lane = threadIdx.x & 63;
    const int w    = threadIdx.x >> 6;
    if (lane == 0) smem[w] = v;
    __syncthreads();
    if (threadIdx.x == 0) {
        const int nw = (blockDim.x + 63) >> 6;
        float t = 0.f;
        for (int k = 0; k < nw; ++k) t += smem[k];
        out[0] = t;
    }
}

extern "C" void kernel_launch(void* const* d_in, const int* in_sizes, int n_in,
                              void* d_out, int out_size, void* d_ws, size_t ws_size,
                              hipStream_t stream) {
    const float* dij = (const float*)d_in[0];
    const int* ni = (const int*)d_in[2];
    const int* nj = (const int*)d_in[3];
    float* out = (float*)d_out;

    const int n_atoms = in_sizes[1];
    const int n_pairs = in_sizes[2];
    const int n_mol   = n_atoms / 3;

    const int B = 256;
    const int NB_BOND = (n_mol + B - 1) / B;

    // one thread per 4-pair chunk (grid-stride covers any excess)
    const int n4 = n_pairs >> 2;
    int NB_PAIR = (n4 + B - 1) / B;
    if (NB_PAIR < 1)    NB_PAIR = 1;
    if (NB_PAIR > 8192) NB_PAIR = 8192;

    // ws layout: om3 [n_atoms float4] | partials [NB_BOND + NB_PAIR]
    float4* om3      = (float4*)d_ws;
    float*  partials = (float*)((char*)d_ws + (size_t)n_atoms * sizeof(float4));

    k_bond  <<<NB_BOND, B, 0, stream>>>(dij, om3, partials, n_mol);
    k_pair  <<<NB_PAIR, B, 0, stream>>>(ni, nj, dij, om3, partials + NB_BOND, n_pairs);
    k_reduce<<<1, B, 0, stream>>>(partials, NB_BOND + NB_PAIR, out);
}

// Round 4
// 100.453 us; speedup vs baseline: 1.5488x; 1.1367x over previous
//
#include <hip/hip_runtime.h>
#include <math.h>

// ---- constants (double-precision folds to float at compile time) ----
static constexpr double D_CUTOFF   = 7.0;
static constexpr double D_SIGMA    = 3.1589;
static constexpr double D_EPS      = 0.1852;
static constexpr double D_GAMMA    = 0.73612;
static constexpr double D_Q        = 1.1128;
static constexpr double D_OH_EQ    = 0.9419;
static constexpr double D_OH_K     = 1059.162;
static constexpr double D_OH_ALPHA = 2.287;
static constexpr double D_ANG_EQ   = 1.87448;
static constexpr double D_ANG_K    = 87.85;
static constexpr double D_SMEAR    = 1.4;
static constexpr double D_PREF     = 332.0637133;

static constexpr double D_SC6   = (D_SIGMA/D_CUTOFF)*(D_SIGMA/D_CUTOFF)*(D_SIGMA/D_CUTOFF)
                                * (D_SIGMA/D_CUTOFF)*(D_SIGMA/D_CUTOFF)*(D_SIGMA/D_CUTOFF);
static constexpr float F_SIG2      = (float)(D_SIGMA*D_SIGMA);
static constexpr float F_4EPS      = (float)(4.0*D_EPS);
static constexpr float F_LJ_SHIFT  = (float)(-4.0*D_EPS*D_SC6*(D_SC6-1.0));
static constexpr float F_Q         = (float)D_Q;
static constexpr float F_QO        = (float)(-D_Q);
static constexpr float F_QH        = (float)(0.5*D_Q);
static constexpr float F_PREF      = (float)D_PREF;
static constexpr float F_INV_S2S   = (float)(1.0/(1.4142135623730951*D_SMEAR));
static constexpr float F_OMG       = (float)((1.0-D_GAMMA)*0.5);
static constexpr float F_OH_EQ     = (float)D_OH_EQ;
static constexpr float F_OH_K      = (float)D_OH_K;
static constexpr float F_OH_ALPHA  = (float)D_OH_ALPHA;
static constexpr float F_ANG_EQ    = (float)D_ANG_EQ;
static constexpr float F_ANG_K     = (float)D_ANG_K;

// ---- fast erfc (A&S 7.1.26, |abs err| <= 1.5e-7) ----
__device__ __forceinline__ float fast_erfc(float x) {
    const float t = __builtin_amdgcn_rcpf(fmaf(0.3275911f, x, 1.0f));
    float p = fmaf(1.061405429f, t, -1.453152027f);
    p = fmaf(p, t, 1.421413741f);
    p = fmaf(p, t, -0.284496736f);
    p = fmaf(p, t, 0.254829592f);
    p *= t;
    return p * __expf(-x * x);
}

// ---- block-wide sum; thread 0 stores to *dst (no atomics, no fences) ----
__device__ __forceinline__ void block_reduce_store(float v, float* dst) {
#pragma unroll
    for (int o = 32; o > 0; o >>= 1) v += __shfl_down(v, o, 64);
    __shared__ float smem[8];
    const int lane = threadIdx.x & 63;
    const int w    = threadIdx.x >> 6;
    if (lane == 0) smem[w] = v;
    __syncthreads();
    if (threadIdx.x == 0) {
        const int nw = (blockDim.x + 63) >> 6;
        float t = 0.f;
        for (int k = 0; k < nw; ++k) t += smem[k];
        *dst = t;
    }
}

__device__ __forceinline__ float bond_e(float r) {
    const float dr  = r - F_OH_EQ;
    const float adr = dr * F_OH_ALPHA;
    return 0.5f * F_OH_K * dr * dr * (1.f - adr + adr * adr * (7.f / 12.f));
}

// ---- per-endpoint m-site offset + charge, computed ON THE FLY from the
//      read-only dij input (bond rows m and n_mol+m of molecule m).
//      No precomputed table -> no producer kernel, no dirty cross-XCD lines.
//      Neighbor-list (ai,aj)-run structure makes the O-branch wave-uniform. ----
__device__ __forceinline__ void endpoint(int a, int n_mol, const float* __restrict__ dij,
                                         float& ox, float& oy, float& oz, float& q) {
    const unsigned m  = (unsigned)a / 3u;
    const bool   isO  = (a == (int)(3u * m));
    ox = 0.f; oy = 0.f; oz = 0.f; q = F_QH;
    if (isO) {
        const float* r1 = dij + 3u * m;
        const float* r2 = dij + 3u * (unsigned)(n_mol + (int)m);
        ox = F_OMG * (r1[0] + r2[0]);
        oy = F_OMG * (r1[1] + r2[1]);
        oz = F_OMG * (r1[2] + r2[2]);
        q  = F_QO;
    }
}

// ---- per-pair LJ + screened Coulomb ----
__device__ __forceinline__ float pair_e(int i, int j, float dx, float dy, float dz,
                                        const float* __restrict__ dij, int n_mol) {
    float oix, oiy, oiz, qi;
    float ojx, ojy, ojz, qj;
    endpoint(i, n_mol, dij, oix, oiy, oiz, qi);
    endpoint(j, n_mol, dij, ojx, ojy, ojz, qj);
    const float mx = dx + ojx - oix;
    const float my = dy + ojy - oiy;
    const float mz = dz + ojz - oiz;
    const float r2m   = mx*mx + my*my + mz*mz;
    const float invrm = __builtin_amdgcn_rsqf(r2m);
    const float rm    = r2m * invrm;
    float e = F_PREF * (qi * qj) * fast_erfc(rm * F_INV_S2S) * invrm;
    if (qi < 0.f && qj < 0.f) {   // both oxygen -> LJ
        const float r2 = dx*dx + dy*dy + dz*dz;
        const float s2 = F_SIG2 * __builtin_amdgcn_rcpf(r2);
        const float c6 = s2 * s2 * s2;
        e += fmaf(F_4EPS, c6 * c6 - c6, F_LJ_SHIFT);
    }
    return e;
}

// ---- fused kernel: pair energies (grid-stride over 4-pair chunks) +
//      bond/bend/self for the first n_mol threads. One partial per block. ----
__global__ void k_main(const int* __restrict__ ni, const int* __restrict__ nj,
                       const float* __restrict__ dij, float* __restrict__ partial,
                       int n_pairs, int n_mol) {
    const int tid = blockIdx.x * blockDim.x + threadIdx.x;
    const int nth = gridDim.x * blockDim.x;
    float e = 0.f;

    // --- bond / bend / self for molecule m (first n_mol threads) ---
    if (tid < n_mol) {
        const int m = tid;
        const float* d1 = dij + 3 * (size_t)m;
        const float* d2 = dij + 3 * (size_t)(n_mol + m);
        const float x1 = d1[0], y1 = d1[1], z1 = d1[2];
        const float x2 = d2[0], y2 = d2[1], z2 = d2[2];
        const float r1 = sqrtf(x1*x1 + y1*y1 + z1*z1);
        const float r2 = sqrtf(x2*x2 + y2*y2 + z2*z2);
        e += bond_e(r1) + bond_e(r2);
        const float ca  = (x1*x2 + y1*y2 + z1*z2) * __builtin_amdgcn_rcpf(r1 * r2);
        const float da  = acosf(ca) - F_ANG_EQ;
        e += 0.5f * F_ANG_K * da * da;
        const float ox = F_OMG * (x1 + x2), oy = F_OMG * (y1 + y2), oz = F_OMG * (z1 + z2);
        // minus e_self = (inv_mh*Q - inv_hh*0.5Q) * 0.5Q * PREF
        const float ax = x1-ox, ay = y1-oy, az = z1-oz;
        const float bx = x2-ox, by = y2-oy, bz = z2-oz;
        const float hx = x1-x2, hy = y1-y2, hz = z1-z2;
        const float inv_mh = __builtin_amdgcn_rsqf(ax*ax+ay*ay+az*az)
                           + __builtin_amdgcn_rsqf(bx*bx+by*by+bz*bz);
        const float inv_hh = __builtin_amdgcn_rsqf(hx*hx+hy*hy+hz*hz);
        e += (inv_mh * F_Q - inv_hh * 0.5f * F_Q) * (0.5f * F_Q * F_PREF);
    }

    // --- pair energies: 4 pairs per chunk, dwordx4 streams ---
    const int n4 = n_pairs >> 2;
    const int4*   ni4 = (const int4*)ni;
    const int4*   nj4 = (const int4*)nj;
    const float4* d4  = (const float4*)dij;
    for (int c = tid; c < n4; c += nth) {
        const int4   ia = ni4[c];
        const int4   ja = nj4[c];
        const float4 a0 = d4[3 * c + 0];
        const float4 a1 = d4[3 * c + 1];
        const float4 a2 = d4[3 * c + 2];
        e += pair_e(ia.x, ja.x, a0.x, a0.y, a0.z, dij, n_mol);
        e += pair_e(ia.y, ja.y, a0.w, a1.x, a1.y, dij, n_mol);
        e += pair_e(ia.z, ja.z, a1.z, a1.w, a2.x, dij, n_mol);
        e += pair_e(ia.w, ja.w, a2.y, a2.z, a2.w, dij, n_mol);
    }
    // tail (<4 pairs)
    for (int p = 4 * n4 + tid; p < n_pairs; p += nth) {
        const size_t b = 3 * (size_t)p;
        e += pair_e(ni[p], nj[p], dij[b + 0], dij[b + 1], dij[b + 2], dij, n_mol);
    }

    block_reduce_store(e, partial + blockIdx.x);
}

// ---- final reduction of all partials -> out[0] ----
__global__ void k_reduce(const float* __restrict__ partial, int n, float* __restrict__ out) {
    float v = 0.f;
    for (int i = threadIdx.x; i < n; i += blockDim.x) v += partial[i];
#pragma unroll
    for (int o = 32; o > 0; o >>= 1) v += __shfl_down(v, o, 64);
    __shared__ float smem[8];
    const int lane = threadIdx.x & 63;
    const int w    = threadIdx.x >> 6;
    if (lane == 0) smem[w] = v;
    __syncthreads();
    if (threadIdx.x == 0) {
        const int nw = (blockDim.x + 63) >> 6;
        float t = 0.f;
        for (int k = 0; k < nw; ++k) t += smem[k];
        out[0] = t;
    }
}

extern "C" void kernel_launch(void* const* d_in, const int* in_sizes, int n_in,
                              void* d_out, int out_size, void* d_ws, size_t ws_size,
                              hipStream_t stream) {
    const float* dij = (const float*)d_in[0];
    const int* ni = (const int*)d_in[2];
    const int* nj = (const int*)d_in[3];
    float* out = (float*)d_out;

    const int n_atoms = in_sizes[1];
    const int n_pairs = in_sizes[2];
    const int n_mol   = n_atoms / 3;

    const int B = 256;
    const int n4 = n_pairs >> 2;
    int NB = (n4 + B - 1) / B;                       // one 4-pair chunk per thread
    const int NB_BOND = (n_mol + B - 1) / B;
    if (NB < NB_BOND) NB = NB_BOND;                  // must cover bond threads
    if (NB > 4096)    NB = 4096;                     // grid-stride covers excess

    // ws layout: partials [NB]
    float* partials = (float*)d_ws;

    k_main  <<<NB, B, 0, stream>>>(ni, nj, dij, partials, n_pairs, n_mol);
    k_reduce<<<1, B, 0, stream>>>(partials, NB, out);
}